// Round 4
// baseline (805.069 us; speedup 1.0000x reference)
//
#include <hip/hip_runtime.h>

// GraphConvNorm: scatter-mean by (row*7+edge_type) -> [N,896]@[896,128] -> BatchNorm.
// N=100000, C=128, E=700000, 7 edge types.
// Dtypes (established over rounds 1-3): x/w/gamma/beta f32 storage (bf16-quantized
// values), indices auto-detected int32/int64, OUTPUT f32 (round-2/3's 8.47 error was
// bf16-packed writes into an f32-decoded buffer).
// Strategy: y[j,t]=x[j]@W_t (bf16 MFMA GEMM; t<6 stored bf16 in ws, t==6 written f32
// directly to d_out = self-slot + accumulator init). Then per-edge atomic scatter
// y[col,et]/cnt[row,et] into d_out[row]. Then 2-pass BatchNorm in place (f32).
// ws: y 153.6MB + cnt 2.8MB + stats/flag ~1KB.

typedef __bf16  bf16x8 __attribute__((ext_vector_type(8)));
typedef float   f32x4  __attribute__((ext_vector_type(4)));
typedef short   short8 __attribute__((ext_vector_type(8)));

union ABFrag { short8 s; bf16x8 b; };

__device__ inline unsigned short f2bfbits(float f) {
    union { float f; unsigned int u; } v; v.f = f;
    unsigned int u = v.u;
    u += 0x7fffu + ((u >> 16) & 1u);   // RNE
    return (unsigned short)(u >> 16);
}

#define LDS_STRIDE 136  // 272B row stride: b128 reads = 2 lanes/bank pair = free (m136)

// [N,128] @ [128, 7*128]: block = 256 thr (4 waves), M-tile 64 (16 rows/wave).
__global__ __launch_bounds__(256) void gemm_xw(
    const float* __restrict__ x,            // [N,128] f32
    const float* __restrict__ w,            // [896,128] f32
    unsigned short* __restrict__ y,         // [N,6,128] bf16 bits (ws)
    float* __restrict__ out_acc,            // [N,128] f32 == d_out
    int N)
{
    __shared__ short lds[128 * LDS_STRIDE]; // W_t transposed bf16: [n][k]

    const int tid  = threadIdx.x;
    const int lane = tid & 63;
    const int wv   = tid >> 6;
    const int quad = lane >> 4;
    const int lr   = lane & 15;

    // A[m=lane&15][k=quad*8+j] per K=32 chunk (m89/m120 layout)
    const int m_load = min(blockIdx.x * 64 + wv * 16 + lr, N - 1);
    const float* xrow = x + (size_t)m_load * 128;
    ABFrag a[4];
#pragma unroll
    for (int kc = 0; kc < 4; ++kc) {
        f32x4 v0 = *(const f32x4*)(xrow + kc * 32 + quad * 8);
        f32x4 v1 = *(const f32x4*)(xrow + kc * 32 + quad * 8 + 4);
#pragma unroll
        for (int j = 0; j < 4; ++j) {
            a[kc].s[j]     = (short)f2bfbits(v0[j]);
            a[kc].s[4 + j] = (short)f2bfbits(v1[j]);
        }
    }

    const int m_store = blockIdx.x * 64 + wv * 16 + quad * 4; // + reg r

    const int kk = tid & 15;
    const int n0 = (tid >> 4) << 3;

    for (int t = 0; t < 7; ++t) {
        __syncthreads();
#pragma unroll
        for (int p = 0; p < 8; ++p) {
            int k = p * 16 + kk;
            const float* wr = w + ((size_t)t * 128 + k) * 128 + n0;
            f32x4 v0 = *(const f32x4*)wr;
            f32x4 v1 = *(const f32x4*)(wr + 4);
#pragma unroll
            for (int j = 0; j < 4; ++j) {
                lds[(n0 + j) * LDS_STRIDE + k]     = (short)f2bfbits(v0[j]);
                lds[(n0 + 4 + j) * LDS_STRIDE + k] = (short)f2bfbits(v1[j]);
            }
        }
        __syncthreads();

#pragma unroll
        for (int nt = 0; nt < 8; ++nt) {
            f32x4 acc = {0.f, 0.f, 0.f, 0.f};
#pragma unroll
            for (int kc = 0; kc < 4; ++kc) {
                ABFrag b;   // B[k=quad*8+j][n=lane&15]
                b.s = *(const short8*)&lds[(nt * 16 + lr) * LDS_STRIDE + kc * 32 + quad * 8];
                acc = __builtin_amdgcn_mfma_f32_16x16x32_bf16(a[kc].b, b.b, acc, 0, 0, 0);
            }
            const int ncol = nt * 16 + lr;
            if (t < 6) {
#pragma unroll
                for (int r = 0; r < 4; ++r) {
                    int m = m_store + r;   // C/D: col=lane&15, row=quad*4+reg (m89)
                    if (m < N) y[((size_t)m * 6 + t) * 128 + ncol] = f2bfbits(acc[r]);
                }
            } else {
#pragma unroll
                for (int r = 0; r < 4; ++r) {
                    int m = m_store + r;
                    if (m < N) out_acc[(size_t)m * 128 + ncol] = acc[r];
                }
            }
        }
    }
}

// Detect index element width from data: int64 => odd 32-bit words (high halves) all 0.
__global__ void flag_k(const int* __restrict__ row, int* __restrict__ flag)
{
    if (threadIdx.x == 0 && blockIdx.x == 0) {
        int s = 0;
#pragma unroll
        for (int i = 1; i < 64; i += 2) s |= row[i];
        flag[0] = (s == 0) ? 1 : 0;   // 1 => int64 (stride-2 low words, LE)
    }
}

__device__ inline int idx_at(const int* __restrict__ p, int e, int mode) {
    return p[mode ? (e << 1) : e];
}

__global__ void count_k(const int* __restrict__ row, const int* __restrict__ et,
                        const int* __restrict__ flag,
                        unsigned int* __restrict__ cnt, int E, int N)
{
    int e = blockIdx.x * blockDim.x + threadIdx.x;
    if (e >= E) return;
    const int mode = flag[0];
    int r = idx_at(row, e, mode);
    int t = idx_at(et,  e, mode);
    if ((unsigned)r < (unsigned)N && (unsigned)t < 7u)
        atomicAdd(&cnt[r * 7 + t], 1u);
}

// one edge per wave; lane handles channels 2*lane, 2*lane+1
__global__ __launch_bounds__(256) void scatter_k(
    const int* __restrict__ row, const int* __restrict__ col,
    const int* __restrict__ et, const int* __restrict__ flag,
    const unsigned int* __restrict__ y2,   // y viewed as bf16x2 words
    const unsigned int* __restrict__ cnt,
    float* __restrict__ out_acc, int E, int N)
{
    int gw   = (blockIdx.x * 256 + threadIdx.x) >> 6;
    int lane = threadIdx.x & 63;
    if (gw >= E) return;
    const int mode = flag[0];
    int t = idx_at(et, gw, mode);
    if (t == 6) return;                    // self-slot overwritten; dead edges
    int r = idx_at(row, gw, mode);
    int c = idx_at(col, gw, mode);
    if ((unsigned)t >= 7u || (unsigned)r >= (unsigned)N || (unsigned)c >= (unsigned)N)
        return;                            // safety net if width guess is wrong
    float inv = 1.0f / (float)max(cnt[r * 7 + t], 1u);
    unsigned int p = y2[((size_t)c * 6 + t) * 64 + lane];
    union { unsigned int u; float f; } lo, hi;
    lo.u = p << 16;
    hi.u = p & 0xffff0000u;
    atomicAdd(&out_acc[(size_t)r * 128 + 2 * lane],     lo.f * inv);
    atomicAdd(&out_acc[(size_t)r * 128 + 2 * lane + 1], hi.f * inv);
}

__global__ __launch_bounds__(256) void stats_k(
    const float* __restrict__ out_acc, float* __restrict__ stats, int N)
{
    float s = 0.f, s2 = 0.f;
    const size_t total = (size_t)N * 128;
    for (size_t i = (size_t)blockIdx.x * 256 + threadIdx.x; i < total;
         i += (size_t)gridDim.x * 256) {     // stride multiple of 128: per-channel
        float v = out_acc[i];
        s += v; s2 += v * v;
    }
    __shared__ float red[2][256];
    red[0][threadIdx.x] = s;
    red[1][threadIdx.x] = s2;
    __syncthreads();
    if (threadIdx.x < 128) {
        s  = red[0][threadIdx.x] + red[0][threadIdx.x + 128];
        s2 = red[1][threadIdx.x] + red[1][threadIdx.x + 128];
        atomicAdd(&stats[threadIdx.x],       s);
        atomicAdd(&stats[128 + threadIdx.x], s2);
    }
}

// In-place BatchNorm finalize, f32 output.
__global__ __launch_bounds__(256) void norm_k(
    float* __restrict__ out, const float* __restrict__ stats,
    const float* __restrict__ gamma, const float* __restrict__ beta, int N)
{
    const int c = threadIdx.x & 127;
    const float invN  = 1.0f / (float)N;
    const float mean  = stats[c] * invN;
    const float var   = stats[128 + c] * invN - mean * mean;
    const float scale = gamma[c] * rsqrtf(var + 1e-5f);
    const float bias  = beta[c] - mean * scale;
    const size_t total = (size_t)N * 128;
    for (size_t i = (size_t)blockIdx.x * 256 + threadIdx.x; i < total;
         i += (size_t)gridDim.x * 256) {
        out[i] = out[i] * scale + bias;
    }
}

extern "C" void kernel_launch(void* const* d_in, const int* in_sizes, int n_in,
                              void* d_out, int out_size, void* d_ws, size_t ws_size,
                              hipStream_t stream)
{
    const float* x     = (const float*)d_in[0];
    const int*   row   = (const int*)d_in[1];
    const int*   col   = (const int*)d_in[2];
    const int*   etype = (const int*)d_in[3];
    const float* w     = (const float*)d_in[4];
    const float* gamma = (const float*)d_in[5];
    const float* beta  = (const float*)d_in[6];
    float* out = (float*)d_out;            // f32 output == accumulator

    const int N = in_sizes[0] / 128;   // 100000
    const int E = in_sizes[1];         // 700000

    char* ws = (char*)d_ws;
    unsigned short* y     = (unsigned short*)ws;                        // N*6*128 bf16
    unsigned int*   cnt   = (unsigned int*)(ws + (size_t)N * 6 * 128 * 2); // 7N u32
    float*          stats = (float*)((char*)cnt + (size_t)N * 7 * 4);   // 256 f32
    int*            flag  = (int*)((char*)stats + 256 * 4);             // 1 int

    hipMemsetAsync(cnt,   0, (size_t)N * 7 * 4, stream);
    hipMemsetAsync(stats, 0, 256 * 4,           stream);

    flag_k<<<1, 64, 0, stream>>>(row, flag);
    count_k<<<(E + 255) / 256, 256, 0, stream>>>(row, etype, flag, cnt, E, N);
    gemm_xw<<<(N + 63) / 64, 256, 0, stream>>>(x, w, y, out, N);
    scatter_k<<<(E + 3) / 4, 256, 0, stream>>>(row, col, etype, flag,
                                               (const unsigned int*)y, cnt, out, E, N);
    stats_k<<<1024, 256, 0, stream>>>(out, stats, N);
    norm_k<<<4096, 256, 0, stream>>>(out, stats, gamma, beta, N);
}

// Round 5
// 443.303 us; speedup vs baseline: 1.8161x; 1.8161x over previous
//
#include <hip/hip_runtime.h>

// GraphConvNorm: scatter-mean by (row*7+edge_type) -> [N,896]@[896,128] -> BatchNorm.
// N=100000, C=128, E=700000, 7 edge types.
// Dtypes (established r1-r4): x/w/gamma/beta f32 (bf16-quantized values), indices
// auto-detected int32/int64, output f32.
// r4 profile: scatter_k (76.8M f32 global atomics) = 496/805 us, 19% HBM, 8.6% VALU.
// r5: destination-grouped gather. edge_k buckets edges by row (capacity 32, Poisson(7)
// => overflow prob ~3e-8; ovf_k atomic fallback keeps any data correct). gather_k:
// one wave per node, register accumulate, one coalesced store. Zero hot-path atomics.
// ws: y 153.6MB + cnt 2.8 + fill 0.4 + ebuf 12.8 + ovf 2.8 + stats/flag/novf ~1KB.

typedef __bf16  bf16x8 __attribute__((ext_vector_type(8)));
typedef float   f32x4  __attribute__((ext_vector_type(4)));
typedef float   f32x2  __attribute__((ext_vector_type(2)));
typedef short   short8 __attribute__((ext_vector_type(8)));

union ABFrag { short8 s; bf16x8 b; };

__device__ inline unsigned short f2bfbits(float f) {
    union { float f; unsigned int u; } v; v.f = f;
    unsigned int u = v.u;
    u += 0x7fffu + ((u >> 16) & 1u);   // RNE
    return (unsigned short)(u >> 16);
}
__device__ inline float bflo(unsigned int p) {
    union { unsigned int u; float f; } v; v.u = p << 16; return v.f;
}
__device__ inline float bfhi(unsigned int p) {
    union { unsigned int u; float f; } v; v.u = p & 0xffff0000u; return v.f;
}

#define LDS_STRIDE 136
#define BUCKET_CAP 32

// ---- GEMM: [N,128] @ [128,7*128]. t<6 -> y bf16; t==6 -> out f32 (self slot). ----
__global__ __launch_bounds__(256) void gemm_xw(
    const float* __restrict__ x, const float* __restrict__ w,
    unsigned short* __restrict__ y, float* __restrict__ out_acc, int N)
{
    __shared__ short lds[128 * LDS_STRIDE];

    const int tid  = threadIdx.x;
    const int lane = tid & 63;
    const int wv   = tid >> 6;
    const int quad = lane >> 4;
    const int lr   = lane & 15;

    const int m_load = min(blockIdx.x * 64 + wv * 16 + lr, N - 1);
    const float* xrow = x + (size_t)m_load * 128;
    ABFrag a[4];
#pragma unroll
    for (int kc = 0; kc < 4; ++kc) {
        f32x4 v0 = *(const f32x4*)(xrow + kc * 32 + quad * 8);
        f32x4 v1 = *(const f32x4*)(xrow + kc * 32 + quad * 8 + 4);
#pragma unroll
        for (int j = 0; j < 4; ++j) {
            a[kc].s[j]     = (short)f2bfbits(v0[j]);
            a[kc].s[4 + j] = (short)f2bfbits(v1[j]);
        }
    }

    const int m_store = blockIdx.x * 64 + wv * 16 + quad * 4;
    const int kk = tid & 15;
    const int n0 = (tid >> 4) << 3;

    for (int t = 0; t < 7; ++t) {
        __syncthreads();
#pragma unroll
        for (int p = 0; p < 8; ++p) {
            int k = p * 16 + kk;
            const float* wr = w + ((size_t)t * 128 + k) * 128 + n0;
            f32x4 v0 = *(const f32x4*)wr;
            f32x4 v1 = *(const f32x4*)(wr + 4);
#pragma unroll
            for (int j = 0; j < 4; ++j) {
                lds[(n0 + j) * LDS_STRIDE + k]     = (short)f2bfbits(v0[j]);
                lds[(n0 + 4 + j) * LDS_STRIDE + k] = (short)f2bfbits(v1[j]);
            }
        }
        __syncthreads();

#pragma unroll
        for (int nt = 0; nt < 8; ++nt) {
            f32x4 acc = {0.f, 0.f, 0.f, 0.f};
#pragma unroll
            for (int kc = 0; kc < 4; ++kc) {
                ABFrag b;
                b.s = *(const short8*)&lds[(nt * 16 + lr) * LDS_STRIDE + kc * 32 + quad * 8];
                acc = __builtin_amdgcn_mfma_f32_16x16x32_bf16(a[kc].b, b.b, acc, 0, 0, 0);
            }
            const int ncol = nt * 16 + lr;
            if (t < 6) {
#pragma unroll
                for (int r = 0; r < 4; ++r) {
                    int m = m_store + r;
                    if (m < N) y[((size_t)m * 6 + t) * 128 + ncol] = f2bfbits(acc[r]);
                }
            } else {
#pragma unroll
                for (int r = 0; r < 4; ++r) {
                    int m = m_store + r;
                    if (m < N) out_acc[(size_t)m * 128 + ncol] = acc[r];
                }
            }
        }
    }
}

// ---- index width autodetect: int64 => odd 32-bit words all zero ----
__global__ void flag_k(const int* __restrict__ row, int* __restrict__ flag)
{
    if (threadIdx.x == 0 && blockIdx.x == 0) {
        int s = 0;
#pragma unroll
        for (int i = 1; i < 64; i += 2) s |= row[i];
        flag[0] = (s == 0) ? 1 : 0;
    }
}
__device__ inline int idx_at(const int* __restrict__ p, int e, int mode) {
    return p[mode ? (e << 1) : e];
}

// ---- fused count + bucket-by-destination ----
__global__ void edge_k(const int* __restrict__ row, const int* __restrict__ col,
                       const int* __restrict__ et, const int* __restrict__ flag,
                       unsigned int* __restrict__ cnt, unsigned int* __restrict__ fill,
                       int* __restrict__ ebuf, int* __restrict__ ovf,
                       int* __restrict__ novf, int E, int N)
{
    int e = blockIdx.x * blockDim.x + threadIdx.x;
    if (e >= E) return;
    const int mode = flag[0];
    int r = idx_at(row, e, mode);
    int c = idx_at(col, e, mode);
    int t = idx_at(et,  e, mode);
    if ((unsigned)r >= (unsigned)N || (unsigned)c >= (unsigned)N || (unsigned)t >= 7u)
        return;
    atomicAdd(&cnt[r * 7 + t], 1u);
    if (t == 6) return;                       // self slot is overwritten: dead edge
    unsigned pos = atomicAdd(&fill[r], 1u);
    if (pos < BUCKET_CAP) ebuf[r * BUCKET_CAP + pos] = (c << 3) | t;
    else                  ovf[atomicAdd(novf, 1)] = e;
}

// ---- one wave per node: register accumulate, single store ----
__global__ __launch_bounds__(256) void gather_k(
    const int* __restrict__ ebuf, const unsigned int* __restrict__ fill,
    const unsigned int* __restrict__ cnt,
    const unsigned int* __restrict__ y2,   // y as bf16x2 words: [(c*6+t)*64 + lane]
    float* __restrict__ out, int N)
{
    int gw   = (blockIdx.x * 256 + threadIdx.x) >> 6;
    int lane = threadIdx.x & 63;
    if (gw >= N) return;
    const int r = gw;

    f32x2 acc = *(const f32x2*)(out + (size_t)r * 128 + 2 * lane); // self term (f32)
    const unsigned nE = min(fill[r], (unsigned)BUCKET_CAP);
    const int* eb = ebuf + (size_t)r * BUCKET_CAP;
    for (unsigned k = 0; k < nE; ++k) {
        int payload = eb[k];
        int c = payload >> 3;
        int t = payload & 7;
        float inv = 1.0f / (float)max(cnt[r * 7 + t], 1u);
        unsigned p = y2[((size_t)(c * 6 + t)) * 64 + lane];
        acc[0] += bflo(p) * inv;
        acc[1] += bfhi(p) * inv;
    }
    *(f32x2*)(out + (size_t)r * 128 + 2 * lane) = acc;
}

// ---- overflow fallback (normally zero work) ----
__global__ void ovf_k(const int* __restrict__ ovf, const int* __restrict__ novf,
                      const int* __restrict__ row, const int* __restrict__ col,
                      const int* __restrict__ et, const int* __restrict__ flag,
                      const unsigned int* __restrict__ y2,
                      const unsigned int* __restrict__ cnt,
                      float* __restrict__ out, int N)
{
    const int n = novf[0];
    const int mode = flag[0];
    for (int i = blockIdx.x * blockDim.x + threadIdx.x; i < n;
         i += gridDim.x * blockDim.x) {
        int e = ovf[i];
        int r = idx_at(row, e, mode);
        int c = idx_at(col, e, mode);
        int t = idx_at(et,  e, mode);
        float inv = 1.0f / (float)max(cnt[r * 7 + t], 1u);
        for (int h = 0; h < 64; ++h) {
            unsigned p = y2[((size_t)(c * 6 + t)) * 64 + h];
            atomicAdd(&out[(size_t)r * 128 + 2 * h],     bflo(p) * inv);
            atomicAdd(&out[(size_t)r * 128 + 2 * h + 1], bfhi(p) * inv);
        }
    }
}

__global__ __launch_bounds__(256) void stats_k(
    const float* __restrict__ out_acc, float* __restrict__ stats, int N)
{
    float s = 0.f, s2 = 0.f;
    const size_t total = (size_t)N * 128;
    for (size_t i = (size_t)blockIdx.x * 256 + threadIdx.x; i < total;
         i += (size_t)gridDim.x * 256) {
        float v = out_acc[i];
        s += v; s2 += v * v;
    }
    __shared__ float red[2][256];
    red[0][threadIdx.x] = s;
    red[1][threadIdx.x] = s2;
    __syncthreads();
    if (threadIdx.x < 128) {
        s  = red[0][threadIdx.x] + red[0][threadIdx.x + 128];
        s2 = red[1][threadIdx.x] + red[1][threadIdx.x + 128];
        atomicAdd(&stats[threadIdx.x],       s);
        atomicAdd(&stats[128 + threadIdx.x], s2);
    }
}

__global__ __launch_bounds__(256) void norm_k(
    float* __restrict__ out, const float* __restrict__ stats,
    const float* __restrict__ gamma, const float* __restrict__ beta, int N)
{
    const int c = threadIdx.x & 127;
    const float invN  = 1.0f / (float)N;
    const float mean  = stats[c] * invN;
    const float var   = stats[128 + c] * invN - mean * mean;
    const float scale = gamma[c] * rsqrtf(var + 1e-5f);
    const float bias  = beta[c] - mean * scale;
    const size_t total = (size_t)N * 128;
    for (size_t i = (size_t)blockIdx.x * 256 + threadIdx.x; i < total;
         i += (size_t)gridDim.x * 256) {
        out[i] = out[i] * scale + bias;
    }
}

extern "C" void kernel_launch(void* const* d_in, const int* in_sizes, int n_in,
                              void* d_out, int out_size, void* d_ws, size_t ws_size,
                              hipStream_t stream)
{
    const float* x     = (const float*)d_in[0];
    const int*   row   = (const int*)d_in[1];
    const int*   col   = (const int*)d_in[2];
    const int*   etype = (const int*)d_in[3];
    const float* w     = (const float*)d_in[4];
    const float* gamma = (const float*)d_in[5];
    const float* beta  = (const float*)d_in[6];
    float* out = (float*)d_out;

    const int N = in_sizes[0] / 128;   // 100000
    const int E = in_sizes[1];         // 700000

    char* ws = (char*)d_ws;
    unsigned short* y     = (unsigned short*)ws;                           // N*6*128 bf16
    unsigned int*   cnt   = (unsigned int*)(ws + (size_t)N * 6 * 128 * 2); // 7N u32
    unsigned int*   fill  = (unsigned int*)((char*)cnt + (size_t)N * 7 * 4); // N u32
    int*            ebuf  = (int*)((char*)fill + (size_t)N * 4);           // N*32 int
    int*            ovf   = (int*)((char*)ebuf + (size_t)N * BUCKET_CAP * 4); // E int
    float*          stats = (float*)((char*)ovf + (size_t)E * 4);          // 256 f32
    int*            flag  = (int*)((char*)stats + 256 * 4);                // 1 int
    int*            novf  = flag + 1;                                      // 1 int

    hipMemsetAsync(cnt,  0, (size_t)N * 7 * 4, stream);
    hipMemsetAsync(fill, 0, (size_t)N * 4,     stream);
    hipMemsetAsync(stats, 0, 256 * 4 + 8,      stream);   // stats + flag + novf

    flag_k<<<1, 64, 0, stream>>>(row, flag);
    edge_k<<<(E + 255) / 256, 256, 0, stream>>>(row, col, etype, flag,
                                                cnt, fill, ebuf, ovf, novf, E, N);
    gemm_xw<<<(N + 63) / 64, 256, 0, stream>>>(x, w, y, out, N);
    gather_k<<<(N + 3) / 4, 256, 0, stream>>>(ebuf, fill, cnt,
                                              (const unsigned int*)y, out, N);
    ovf_k<<<256, 256, 0, stream>>>(ovf, novf, row, col, etype, flag,
                                   (const unsigned int*)y, cnt, out, N);
    stats_k<<<1024, 256, 0, stream>>>(out, stats, N);
    norm_k<<<4096, 256, 0, stream>>>(out, stats, gamma, beta, N);
}

// Round 6
// 379.239 us; speedup vs baseline: 2.1229x; 1.1689x over previous
//
#include <hip/hip_runtime.h>
#include <hip/hip_bf16.h>

// GraphConvNorm: scatter-mean by (row*7+edge_type) -> [N,896]@[896,128] -> BatchNorm.
// N=100000, C=128, E=700000. x/w/gamma/beta f32, indices auto int32/int64, out f32.
// r5 profile: gemm 146us latency-bound on LDS staging (1.12e7 bank conflicts, 6% MFMA).
// r6: LDS-free gemm. W pre-packed once into MFMA B-fragment order (229KB, L2-hot);
// y [N][7][128] bf16 with paired channels (c,c+64) per u32 -> dwordx4 stores; self
// term lives in y slot 6. gather: wave/node, payload+cnt via shfl, fused BN stats.
// ovf_k repairs out+stats exactly (atomic old-value telescoping). norm un-permutes.
// ws: y 179.2MB + wp 0.23 + cnt 2.8 + fill 0.4 + ebuf 12.8 + ovf 2.8 + stats ~1KB.

typedef float  f32x4  __attribute__((ext_vector_type(4)));
typedef float  f32x2  __attribute__((ext_vector_type(2)));
typedef short  short8 __attribute__((ext_vector_type(8)));
typedef __bf16 bf16x8 __attribute__((ext_vector_type(8)));

union BFrag { uint4 q; short8 s; bf16x8 b; unsigned int u[4]; };

__device__ inline unsigned short f2bfbits(float f) {
    union { float f; unsigned int u; } v; v.f = f;
    unsigned int u = v.u;
    u += 0x7fffu + ((u >> 16) & 1u);   // RNE
    return (unsigned short)(u >> 16);
}
__device__ inline unsigned int pk_bf16(float lo, float hi) {
    float2 f; f.x = lo; f.y = hi;
    union { __hip_bfloat162 h; unsigned int u; } v;
    v.h = __float22bfloat162_rn(f);
    return v.u;
}
__device__ inline float bflo(unsigned int p) {
    union { unsigned int u; float f; } v; v.u = p << 16; return v.f;
}
__device__ inline float bfhi(unsigned int p) {
    union { unsigned int u; float f; } v; v.u = p & 0xffff0000u; return v.f;
}

#define BUCKET_CAP 32

// ---- W [7*128,128] f32 -> bf16 in MFMA B-frag order: [t][nt][kc][lane][j] ----
__global__ void pack_w(const float* __restrict__ w, short8* __restrict__ wp)
{
    int u = blockIdx.x * 256 + threadIdx.x;
    if (u >= 7 * 8 * 4 * 64) return;
    int lane = u & 63, kc = (u >> 6) & 3, nt = (u >> 8) & 7, t = u >> 11;
    int quad = lane >> 4, lr = lane & 15;
    short8 s;
#pragma unroll
    for (int j = 0; j < 8; ++j)
        s[j] = (short)f2bfbits(w[(size_t)(t * 128 + kc * 32 + quad * 8 + j) * 128
                                 + nt * 16 + lr]);
    wp[u] = s;
}

// ---- GEMM: y[m][t] row = 64 u32, word p=lr*4+j holds channels (j*16+lr, +64) ----
__global__ __launch_bounds__(256) void gemm_xw(
    const float* __restrict__ x, const uint4* __restrict__ wpq,
    unsigned int* __restrict__ yu, int N)
{
    const int tid  = threadIdx.x;
    const int lane = tid & 63;
    const int wv   = tid >> 6;
    const int quad = lane >> 4;
    const int lr   = lane & 15;
    const int mbase = blockIdx.x * 128 + wv * 32;

    BFrag a[2][4];   // A[m=lr][k=quad*8+j], two 16-row groups
#pragma unroll
    for (int g = 0; g < 2; ++g)
#pragma unroll
        for (int kc = 0; kc < 4; ++kc) {
            const float* xr = x + (size_t)min(mbase + g * 16 + lr, N - 1) * 128
                              + kc * 32 + quad * 8;
            f32x4 v0 = *(const f32x4*)xr;
            f32x4 v1 = *(const f32x4*)(xr + 4);
            a[g][kc].u[0] = pk_bf16(v0[0], v0[1]);
            a[g][kc].u[1] = pk_bf16(v0[2], v0[3]);
            a[g][kc].u[2] = pk_bf16(v1[0], v1[1]);
            a[g][kc].u[3] = pk_bf16(v1[2], v1[3]);
        }

    for (int t = 0; t < 7; ++t) {
        f32x4 acc[2][8];
#pragma unroll
        for (int g = 0; g < 2; ++g)
#pragma unroll
            for (int nt = 0; nt < 8; ++nt) acc[g][nt] = (f32x4){0.f, 0.f, 0.f, 0.f};

#pragma unroll
        for (int nt = 0; nt < 8; ++nt)
#pragma unroll
            for (int kc = 0; kc < 4; ++kc) {
                BFrag b;
                b.q = wpq[(size_t)(((t * 8 + nt) * 4 + kc) * 64) + lane];
                acc[0][nt] = __builtin_amdgcn_mfma_f32_16x16x32_bf16(a[0][kc].b, b.b, acc[0][nt], 0, 0, 0);
                acc[1][nt] = __builtin_amdgcn_mfma_f32_16x16x32_bf16(a[1][kc].b, b.b, acc[1][nt], 0, 0, 0);
            }

#pragma unroll
        for (int g = 0; g < 2; ++g)
#pragma unroll
            for (int r = 0; r < 4; ++r) {
                int m = mbase + g * 16 + quad * 4 + r;  // C/D: col=lr, row=quad*4+r
                if (m < N) {
                    uint4 o;
                    o.x = pk_bf16(acc[g][0][r], acc[g][4][r]);
                    o.y = pk_bf16(acc[g][1][r], acc[g][5][r]);
                    o.z = pk_bf16(acc[g][2][r], acc[g][6][r]);
                    o.w = pk_bf16(acc[g][3][r], acc[g][7][r]);
                    *(uint4*)(yu + ((size_t)m * 7 + t) * 64 + lr * 4) = o;
                }
            }
    }
}

// ---- index width autodetect ----
__global__ void flag_k(const int* __restrict__ row, int* __restrict__ flag)
{
    if (threadIdx.x == 0 && blockIdx.x == 0) {
        int s = 0;
#pragma unroll
        for (int i = 1; i < 64; i += 2) s |= row[i];
        flag[0] = (s == 0) ? 1 : 0;
    }
}
__device__ inline int idx_at(const int* __restrict__ p, int e, int mode) {
    return p[mode ? (e << 1) : e];
}

// ---- count + bucket (t=6 dead: self slot overwritten) ----
__global__ void edge_k(const int* __restrict__ row, const int* __restrict__ col,
                       const int* __restrict__ et, const int* __restrict__ flag,
                       unsigned int* __restrict__ cnt, unsigned int* __restrict__ fill,
                       int* __restrict__ ebuf, int* __restrict__ ovf,
                       int* __restrict__ novf, int E, int N)
{
    int e = blockIdx.x * blockDim.x + threadIdx.x;
    if (e >= E) return;
    const int mode = flag[0];
    int r = idx_at(row, e, mode);
    int c = idx_at(col, e, mode);
    int t = idx_at(et,  e, mode);
    if ((unsigned)r >= (unsigned)N || (unsigned)c >= (unsigned)N || (unsigned)t >= 6u)
        return;
    atomicAdd(&cnt[r * 7 + t], 1u);
    unsigned pos = atomicAdd(&fill[r], 1u);
    if (pos < BUCKET_CAP) ebuf[(size_t)r * BUCKET_CAP + pos] = (c << 3) | t;
    else                  ovf[atomicAdd(novf, 1)] = e;
}

// ---- wave/node gather + fused BN stats; out in packed-pair f32 layout ----
__global__ __launch_bounds__(256) void gather_k(
    const int* __restrict__ ebuf, const unsigned int* __restrict__ fill,
    const unsigned int* __restrict__ cnt, const unsigned int* __restrict__ yu,
    float* __restrict__ out, float* __restrict__ stats, int N, int nwaves)
{
    const int gw = (blockIdx.x * 256 + threadIdx.x) >> 6;
    const int l  = threadIdx.x & 63;
    const int clo = ((l & 3) << 4) + (l >> 2);     // channel of lo half; hi = clo+64
    float slo = 0.f, slo2 = 0.f, shi = 0.f, shi2 = 0.f;

    for (int r = gw; r < N; r += nwaves) {
        unsigned p = yu[((size_t)r * 7 + 6) * 64 + l];   // self term, weight 1
        float a0 = bflo(p), a1 = bfhi(p);
        const unsigned nE = min(fill[r], (unsigned)BUCKET_CAP);
        float cv  = (l < 7) ? (float)max(cnt[r * 7 + l], 1u) : 1.0f;
        int   pay = (l < (int)nE) ? ebuf[(size_t)r * BUCKET_CAP + l] : 0;
        for (unsigned k = 0; k < nE; ++k) {
            int pk = __shfl(pay, (int)k);
            int c = pk >> 3, t = pk & 7;
            float inv = 1.0f / __shfl(cv, t);
            unsigned q = yu[((size_t)c * 7 + t) * 64 + l];
            a0 += bflo(q) * inv;
            a1 += bfhi(q) * inv;
        }
        f32x2 o; o[0] = a0; o[1] = a1;
        *(f32x2*)(out + (size_t)r * 128 + 2 * l) = o;
        slo += a0; slo2 += a0 * a0; shi += a1; shi2 += a1 * a1;
    }

    __shared__ float rs[4][256];
    rs[0][threadIdx.x] = slo; rs[1][threadIdx.x] = slo2;
    rs[2][threadIdx.x] = shi; rs[3][threadIdx.x] = shi2;
    __syncthreads();
    if (threadIdx.x < 64) {
        float v0 = 0.f, v1 = 0.f, v2 = 0.f, v3 = 0.f;
#pragma unroll
        for (int w = 0; w < 4; ++w) {
            v0 += rs[0][w * 64 + threadIdx.x];
            v1 += rs[1][w * 64 + threadIdx.x];
            v2 += rs[2][w * 64 + threadIdx.x];
            v3 += rs[3][w * 64 + threadIdx.x];
        }
        atomicAdd(&stats[clo],            v0);
        atomicAdd(&stats[128 + clo],      v1);
        atomicAdd(&stats[clo + 64],       v2);
        atomicAdd(&stats[192 + clo],      v3);
    }
}

// ---- overflow repair: wave/edge; fixes out AND stats exactly via returned old ----
__global__ void ovf_k(const int* __restrict__ ovf, const int* __restrict__ novf,
                      const int* __restrict__ row, const int* __restrict__ col,
                      const int* __restrict__ et, const int* __restrict__ flag,
                      const unsigned int* __restrict__ yu,
                      const unsigned int* __restrict__ cnt,
                      float* __restrict__ out, float* __restrict__ stats, int nwaves)
{
    const int n = novf[0];
    if (n == 0) return;
    const int mode = flag[0];
    const int l = threadIdx.x & 63;
    const int clo = ((l & 3) << 4) + (l >> 2);
    for (int i = (blockIdx.x * 256 + threadIdx.x) >> 6; i < n; i += nwaves) {
        int e = ovf[i];
        int r = idx_at(row, e, mode);
        int c = idx_at(col, e, mode);
        int t = idx_at(et,  e, mode);
        float inv = 1.0f / (float)max(cnt[r * 7 + t], 1u);
        unsigned q = yu[((size_t)c * 7 + t) * 64 + l];
        float dlo = bflo(q) * inv, dhi = bfhi(q) * inv;
        float olo = atomicAdd(&out[(size_t)r * 128 + 2 * l],     dlo);
        float ohi = atomicAdd(&out[(size_t)r * 128 + 2 * l + 1], dhi);
        atomicAdd(&stats[clo],       dlo);
        atomicAdd(&stats[128 + clo], dlo * (2.f * olo + dlo));
        atomicAdd(&stats[64 + clo],  dhi);
        atomicAdd(&stats[192 + clo], dhi * (2.f * ohi + dhi));
    }
}

// ---- BN finalize: read packed layout, un-permute via LDS, write standard ----
__global__ __launch_bounds__(256) void norm_k(
    float* __restrict__ out, const float* __restrict__ stats,
    const float* __restrict__ gamma, const float* __restrict__ beta, int N)
{
    __shared__ float sc[128], bi[128], buf[256];
    if (threadIdx.x < 128) {
        int c = threadIdx.x;
        float invN = 1.0f / (float)N;
        float mean = stats[c] * invN;
        float var  = stats[128 + c] * invN - mean * mean;
        float s = gamma[c] * rsqrtf(var + 1e-5f);
        sc[c] = s; bi[c] = beta[c] - mean * s;
    }
    __syncthreads();
    const int p  = threadIdx.x & 127;          // packed position within row
    const int lh = p >> 1;
    const int c  = ((lh & 3) << 4) + (lh >> 2) + ((p & 1) << 6);
    const size_t total = (size_t)N * 128;
    for (size_t base = (size_t)blockIdx.x * 256; base < total;
         base += (size_t)gridDim.x * 256) {
        float v = out[base + threadIdx.x];
        buf[(threadIdx.x & 128) | c] = v * sc[c] + bi[c];
        __syncthreads();
        out[base + threadIdx.x] = buf[threadIdx.x];
        __syncthreads();
    }
}

extern "C" void kernel_launch(void* const* d_in, const int* in_sizes, int n_in,
                              void* d_out, int out_size, void* d_ws, size_t ws_size,
                              hipStream_t stream)
{
    const float* x     = (const float*)d_in[0];
    const int*   row   = (const int*)d_in[1];
    const int*   col   = (const int*)d_in[2];
    const int*   etype = (const int*)d_in[3];
    const float* w     = (const float*)d_in[4];
    const float* gamma = (const float*)d_in[5];
    const float* beta  = (const float*)d_in[6];
    float* out = (float*)d_out;

    const int N = in_sizes[0] / 128;   // 100000
    const int E = in_sizes[1];         // 700000

    char* ws = (char*)d_ws;
    unsigned int* yu   = (unsigned int*)ws;                            // N*7*64 u32
    short8*       wp   = (short8*)(ws + (size_t)N * 7 * 256);          // 229376 B
    unsigned int* cnt  = (unsigned int*)((char*)wp + 7 * 8 * 4 * 64 * 16); // 7N u32
    unsigned int* fill = (unsigned int*)((char*)cnt + (size_t)N * 7 * 4); // N u32
    int*          ebuf = (int*)((char*)fill + (size_t)N * 4);          // N*32 int
    int*          ovf  = (int*)((char*)ebuf + (size_t)N * BUCKET_CAP * 4); // E int
    float*        stats= (float*)((char*)ovf + (size_t)E * 4);         // 256 f32
    int*          flag = (int*)((char*)stats + 256 * 4);               // 1 int
    int*          novf = flag + 1;                                     // 1 int

    hipMemsetAsync(cnt,  0, (size_t)N * 7 * 4, stream);
    hipMemsetAsync(fill, 0, (size_t)N * 4,     stream);
    hipMemsetAsync(stats, 0, 256 * 4 + 8,      stream);

    flag_k<<<1, 64, 0, stream>>>(row, flag);
    pack_w<<<(7 * 8 * 4 * 64 + 255) / 256, 256, 0, stream>>>(w, wp);
    edge_k<<<(E + 255) / 256, 256, 0, stream>>>(row, col, etype, flag,
                                                cnt, fill, ebuf, ovf, novf, E, N);
    gemm_xw<<<(N + 127) / 128, 256, 0, stream>>>(x, (const uint4*)wp, yu, N);
    gather_k<<<1024, 256, 0, stream>>>(ebuf, fill, cnt, yu, out, stats, N, 4096);
    ovf_k<<<64, 256, 0, stream>>>(ovf, novf, row, col, etype, flag,
                                  yu, cnt, out, stats, 256);
    norm_k<<<2048, 256, 0, stream>>>(out, stats, gamma, beta, N);
}

// Round 7
// 361.685 us; speedup vs baseline: 2.2259x; 1.0485x over previous
//
#include <hip/hip_runtime.h>
#include <hip/hip_bf16.h>

// GraphConvNorm: scatter-mean by (row*7+edge_type) -> [N,896]@[896,128] -> BatchNorm.
// N=100000, C=128, E=700000. x/w/gamma/beta f32, indices auto int32/int64, out f32.
// r6 profile: gather_k 120us top, latency-bound (VALU 24%, HBM 16%, dynamic edge loop
// => vmcnt(0) per edge). r7: unroll-4 edge loop (4 y-loads in flight), 8192 waves,
// gather stores standard channel layout directly (2 scalar stores, same lines) =>
// norm_k becomes a pure coalesced vec4 affine pass (no LDS, no syncthreads).
// ws: y 179.2MB + wp 0.23 + cnt 2.8 + fill 0.4 + ebuf 12.8 + ovf 2.8 + stats ~1KB.

typedef float  f32x4  __attribute__((ext_vector_type(4)));
typedef short  short8 __attribute__((ext_vector_type(8)));
typedef __bf16 bf16x8 __attribute__((ext_vector_type(8)));

union BFrag { uint4 q; short8 s; bf16x8 b; unsigned int u[4]; };

__device__ inline unsigned short f2bfbits(float f) {
    union { float f; unsigned int u; } v; v.f = f;
    unsigned int u = v.u;
    u += 0x7fffu + ((u >> 16) & 1u);   // RNE
    return (unsigned short)(u >> 16);
}
__device__ inline unsigned int pk_bf16(float lo, float hi) {
    float2 f; f.x = lo; f.y = hi;
    union { __hip_bfloat162 h; unsigned int u; } v;
    v.h = __float22bfloat162_rn(f);
    return v.u;
}
__device__ inline float bflo(unsigned int p) {
    union { unsigned int u; float f; } v; v.u = p << 16; return v.f;
}
__device__ inline float bfhi(unsigned int p) {
    union { unsigned int u; float f; } v; v.u = p & 0xffff0000u; return v.f;
}

#define BUCKET_CAP 32

// ---- W [7*128,128] f32 -> bf16 in MFMA B-frag order: [t][nt][kc][lane][j] ----
__global__ void pack_w(const float* __restrict__ w, short8* __restrict__ wp)
{
    int u = blockIdx.x * 256 + threadIdx.x;
    if (u >= 7 * 8 * 4 * 64) return;
    int lane = u & 63, kc = (u >> 6) & 3, nt = (u >> 8) & 7, t = u >> 11;
    int quad = lane >> 4, lr = lane & 15;
    short8 s;
#pragma unroll
    for (int j = 0; j < 8; ++j)
        s[j] = (short)f2bfbits(w[(size_t)(t * 128 + kc * 32 + quad * 8 + j) * 128
                                 + nt * 16 + lr]);
    wp[u] = s;
}

// ---- GEMM: y[m][t] row = 64 u32, word p=lr*4+j holds channels (j*16+lr, +64) ----
__global__ __launch_bounds__(256) void gemm_xw(
    const float* __restrict__ x, const uint4* __restrict__ wpq,
    unsigned int* __restrict__ yu, int N)
{
    const int tid  = threadIdx.x;
    const int lane = tid & 63;
    const int wv   = tid >> 6;
    const int quad = lane >> 4;
    const int lr   = lane & 15;
    const int mbase = blockIdx.x * 128 + wv * 32;

    BFrag a[2][4];   // A[m=lr][k=quad*8+j], two 16-row groups
#pragma unroll
    for (int g = 0; g < 2; ++g)
#pragma unroll
        for (int kc = 0; kc < 4; ++kc) {
            const float* xr = x + (size_t)min(mbase + g * 16 + lr, N - 1) * 128
                              + kc * 32 + quad * 8;
            f32x4 v0 = *(const f32x4*)xr;
            f32x4 v1 = *(const f32x4*)(xr + 4);
            a[g][kc].u[0] = pk_bf16(v0[0], v0[1]);
            a[g][kc].u[1] = pk_bf16(v0[2], v0[3]);
            a[g][kc].u[2] = pk_bf16(v1[0], v1[1]);
            a[g][kc].u[3] = pk_bf16(v1[2], v1[3]);
        }

    for (int t = 0; t < 7; ++t) {
        f32x4 acc[2][8];
#pragma unroll
        for (int g = 0; g < 2; ++g)
#pragma unroll
            for (int nt = 0; nt < 8; ++nt) acc[g][nt] = (f32x4){0.f, 0.f, 0.f, 0.f};

#pragma unroll
        for (int nt = 0; nt < 8; ++nt)
#pragma unroll
            for (int kc = 0; kc < 4; ++kc) {
                BFrag b;
                b.q = wpq[(size_t)(((t * 8 + nt) * 4 + kc) * 64) + lane];
                acc[0][nt] = __builtin_amdgcn_mfma_f32_16x16x32_bf16(a[0][kc].b, b.b, acc[0][nt], 0, 0, 0);
                acc[1][nt] = __builtin_amdgcn_mfma_f32_16x16x32_bf16(a[1][kc].b, b.b, acc[1][nt], 0, 0, 0);
            }

#pragma unroll
        for (int g = 0; g < 2; ++g)
#pragma unroll
            for (int r = 0; r < 4; ++r) {
                int m = mbase + g * 16 + quad * 4 + r;  // C/D: col=lr, row=quad*4+r
                if (m < N) {
                    uint4 o;
                    o.x = pk_bf16(acc[g][0][r], acc[g][4][r]);
                    o.y = pk_bf16(acc[g][1][r], acc[g][5][r]);
                    o.z = pk_bf16(acc[g][2][r], acc[g][6][r]);
                    o.w = pk_bf16(acc[g][3][r], acc[g][7][r]);
                    *(uint4*)(yu + ((size_t)m * 7 + t) * 64 + lr * 4) = o;
                }
            }
    }
}

// ---- index width autodetect ----
__global__ void flag_k(const int* __restrict__ row, int* __restrict__ flag)
{
    if (threadIdx.x == 0 && blockIdx.x == 0) {
        int s = 0;
#pragma unroll
        for (int i = 1; i < 64; i += 2) s |= row[i];
        flag[0] = (s == 0) ? 1 : 0;
    }
}
__device__ inline int idx_at(const int* __restrict__ p, int e, int mode) {
    return p[mode ? (e << 1) : e];
}

// ---- count + bucket (t=6 dead: self slot overwritten) ----
__global__ void edge_k(const int* __restrict__ row, const int* __restrict__ col,
                       const int* __restrict__ et, const int* __restrict__ flag,
                       unsigned int* __restrict__ cnt, unsigned int* __restrict__ fill,
                       int* __restrict__ ebuf, int* __restrict__ ovf,
                       int* __restrict__ novf, int E, int N)
{
    int e = blockIdx.x * blockDim.x + threadIdx.x;
    if (e >= E) return;
    const int mode = flag[0];
    int r = idx_at(row, e, mode);
    int c = idx_at(col, e, mode);
    int t = idx_at(et,  e, mode);
    if ((unsigned)r >= (unsigned)N || (unsigned)c >= (unsigned)N || (unsigned)t >= 6u)
        return;
    atomicAdd(&cnt[r * 7 + t], 1u);
    unsigned pos = atomicAdd(&fill[r], 1u);
    if (pos < BUCKET_CAP) ebuf[(size_t)r * BUCKET_CAP + pos] = (c << 3) | t;
    else                  ovf[atomicAdd(novf, 1)] = e;
}

// ---- wave/node gather, unroll-4 MLP, fused BN stats, standard-layout store ----
__global__ __launch_bounds__(256) void gather_k(
    const int* __restrict__ ebuf, const unsigned int* __restrict__ fill,
    const unsigned int* __restrict__ cnt, const unsigned int* __restrict__ yu,
    float* __restrict__ out, float* __restrict__ stats, int N, int nwaves)
{
    const int gw = (blockIdx.x * 256 + threadIdx.x) >> 6;
    const int l  = threadIdx.x & 63;
    const int clo = ((l & 3) << 4) + (l >> 2);     // channel of lo half; hi = clo+64
    float slo = 0.f, slo2 = 0.f, shi = 0.f, shi2 = 0.f;

    for (int r = gw; r < N; r += nwaves) {
        unsigned p = yu[((size_t)r * 7 + 6) * 64 + l];   // self term, weight 1
        float a0 = bflo(p), a1 = bfhi(p);
        const int nE = (int)min(fill[r], (unsigned)BUCKET_CAP);
        float cv  = (l < 7) ? (float)max(cnt[r * 7 + l], 1u) : 1.0f;
        int   pay = (l < nE) ? ebuf[(size_t)r * BUCKET_CAP + l] : 0;
        int k = 0;
        for (; k + 4 <= nE; k += 4) {               // 4 loads in flight
            int p0 = __shfl(pay, k);
            int p1 = __shfl(pay, k + 1);
            int p2 = __shfl(pay, k + 2);
            int p3 = __shfl(pay, k + 3);
            unsigned q0 = yu[((size_t)(p0 >> 3) * 7 + (p0 & 7)) * 64 + l];
            unsigned q1 = yu[((size_t)(p1 >> 3) * 7 + (p1 & 7)) * 64 + l];
            unsigned q2 = yu[((size_t)(p2 >> 3) * 7 + (p2 & 7)) * 64 + l];
            unsigned q3 = yu[((size_t)(p3 >> 3) * 7 + (p3 & 7)) * 64 + l];
            float i0 = 1.0f / __shfl(cv, p0 & 7);
            float i1 = 1.0f / __shfl(cv, p1 & 7);
            float i2 = 1.0f / __shfl(cv, p2 & 7);
            float i3 = 1.0f / __shfl(cv, p3 & 7);
            a0 += bflo(q0) * i0; a1 += bfhi(q0) * i0;
            a0 += bflo(q1) * i1; a1 += bfhi(q1) * i1;
            a0 += bflo(q2) * i2; a1 += bfhi(q2) * i2;
            a0 += bflo(q3) * i3; a1 += bfhi(q3) * i3;
        }
        for (; k < nE; ++k) {
            int pk = __shfl(pay, k);
            float inv = 1.0f / __shfl(cv, pk & 7);
            unsigned q = yu[((size_t)(pk >> 3) * 7 + (pk & 7)) * 64 + l];
            a0 += bflo(q) * inv;
            a1 += bfhi(q) * inv;
        }
        out[(size_t)r * 128 + clo]      = a0;   // standard layout (permuted within row)
        out[(size_t)r * 128 + clo + 64] = a1;
        slo += a0; slo2 += a0 * a0; shi += a1; shi2 += a1 * a1;
    }

    __shared__ float rs[4][256];
    rs[0][threadIdx.x] = slo; rs[1][threadIdx.x] = slo2;
    rs[2][threadIdx.x] = shi; rs[3][threadIdx.x] = shi2;
    __syncthreads();
    if (threadIdx.x < 64) {
        float v0 = 0.f, v1 = 0.f, v2 = 0.f, v3 = 0.f;
#pragma unroll
        for (int w = 0; w < 4; ++w) {
            v0 += rs[0][w * 64 + threadIdx.x];
            v1 += rs[1][w * 64 + threadIdx.x];
            v2 += rs[2][w * 64 + threadIdx.x];
            v3 += rs[3][w * 64 + threadIdx.x];
        }
        atomicAdd(&stats[clo],           v0);
        atomicAdd(&stats[128 + clo],     v1);
        atomicAdd(&stats[clo + 64],      v2);
        atomicAdd(&stats[192 + clo],     v3);
    }
}

// ---- overflow repair: wave/edge; fixes out AND stats exactly via returned old ----
__global__ void ovf_k(const int* __restrict__ ovf, const int* __restrict__ novf,
                      const int* __restrict__ row, const int* __restrict__ col,
                      const int* __restrict__ et, const int* __restrict__ flag,
                      const unsigned int* __restrict__ yu,
                      const unsigned int* __restrict__ cnt,
                      float* __restrict__ out, float* __restrict__ stats, int nwaves)
{
    const int n = novf[0];
    if (n == 0) return;
    const int mode = flag[0];
    const int l = threadIdx.x & 63;
    const int clo = ((l & 3) << 4) + (l >> 2);
    for (int i = (blockIdx.x * 256 + threadIdx.x) >> 6; i < n; i += nwaves) {
        int e = ovf[i];
        int r = idx_at(row, e, mode);
        int c = idx_at(col, e, mode);
        int t = idx_at(et,  e, mode);
        float inv = 1.0f / (float)max(cnt[r * 7 + t], 1u);
        unsigned q = yu[((size_t)c * 7 + t) * 64 + l];
        float dlo = bflo(q) * inv, dhi = bfhi(q) * inv;
        float olo = atomicAdd(&out[(size_t)r * 128 + clo],      dlo);
        float ohi = atomicAdd(&out[(size_t)r * 128 + clo + 64], dhi);
        atomicAdd(&stats[clo],       dlo);
        atomicAdd(&stats[128 + clo], dlo * (2.f * olo + dlo));
        atomicAdd(&stats[clo + 64],  dhi);
        atomicAdd(&stats[192 + clo], dhi * (2.f * ohi + dhi));
    }
}

// ---- BN finalize: standard layout, coalesced vec4, no LDS ----
__global__ __launch_bounds__(256) void norm_k(
    float* __restrict__ out, const float* __restrict__ stats,
    const float* __restrict__ gamma, const float* __restrict__ beta, int N)
{
    const int c0 = (threadIdx.x * 4) & 127;     // grid stride is mult. of 128 elems
    const float invN = 1.0f / (float)N;
    f32x4 sc, bi;
#pragma unroll
    for (int j = 0; j < 4; ++j) {
        int c = c0 + j;
        float mean = stats[c] * invN;
        float var  = stats[128 + c] * invN - mean * mean;
        float s = gamma[c] * rsqrtf(var + 1e-5f);
        sc[j] = s; bi[j] = beta[c] - mean * s;
    }
    const size_t nv = (size_t)N * 32;           // vec4 count
    for (size_t v = (size_t)blockIdx.x * 256 + threadIdx.x; v < nv;
         v += (size_t)gridDim.x * 256) {
        f32x4 x = *(f32x4*)(out + v * 4);
#pragma unroll
        for (int j = 0; j < 4; ++j) x[j] = x[j] * sc[j] + bi[j];
        *(f32x4*)(out + v * 4) = x;
    }
}

extern "C" void kernel_launch(void* const* d_in, const int* in_sizes, int n_in,
                              void* d_out, int out_size, void* d_ws, size_t ws_size,
                              hipStream_t stream)
{
    const float* x     = (const float*)d_in[0];
    const int*   row   = (const int*)d_in[1];
    const int*   col   = (const int*)d_in[2];
    const int*   etype = (const int*)d_in[3];
    const float* w     = (const float*)d_in[4];
    const float* gamma = (const float*)d_in[5];
    const float* beta  = (const float*)d_in[6];
    float* out = (float*)d_out;

    const int N = in_sizes[0] / 128;   // 100000
    const int E = in_sizes[1];         // 700000

    char* ws = (char*)d_ws;
    unsigned int* yu   = (unsigned int*)ws;                            // N*7*64 u32
    short8*       wp   = (short8*)(ws + (size_t)N * 7 * 256);          // 229376 B
    unsigned int* cnt  = (unsigned int*)((char*)wp + 7 * 8 * 4 * 64 * 16); // 7N u32
    unsigned int* fill = (unsigned int*)((char*)cnt + (size_t)N * 7 * 4); // N u32
    int*          ebuf = (int*)((char*)fill + (size_t)N * 4);          // N*32 int
    int*          ovf  = (int*)((char*)ebuf + (size_t)N * BUCKET_CAP * 4); // E int
    float*        stats= (float*)((char*)ovf + (size_t)E * 4);         // 256 f32
    int*          flag = (int*)((char*)stats + 256 * 4);               // 1 int
    int*          novf = flag + 1;                                     // 1 int

    hipMemsetAsync(cnt,  0, (size_t)N * 7 * 4, stream);
    hipMemsetAsync(fill, 0, (size_t)N * 4,     stream);
    hipMemsetAsync(stats, 0, 256 * 4 + 8,      stream);

    flag_k<<<1, 64, 0, stream>>>(row, flag);
    pack_w<<<(7 * 8 * 4 * 64 + 255) / 256, 256, 0, stream>>>(w, wp);
    edge_k<<<(E + 255) / 256, 256, 0, stream>>>(row, col, etype, flag,
                                                cnt, fill, ebuf, ovf, novf, E, N);
    gemm_xw<<<(N + 127) / 128, 256, 0, stream>>>(x, (const uint4*)wp, yu, N);
    gather_k<<<2048, 256, 0, stream>>>(ebuf, fill, cnt, yu, out, stats, N, 8192);
    ovf_k<<<64, 256, 0, stream>>>(ovf, novf, row, col, etype, flag,
                                  yu, cnt, out, stats, 256);
    norm_k<<<2048, 256, 0, stream>>>(out, stats, gamma, beta, N);
}